// Round 3
// baseline (486.045 us; speedup 1.0000x reference)
//
#include <hip/hip_runtime.h>
#include <math.h>
#include <stdint.h>

#define ALPHA 0.1f
#define EPS 1e-7f

constexpr int D = 65;                  // 1 time-like + 64 space dims
constexpr int A = 16;                  // anchors
constexpr int RPW = 64;                // rows per tile (one wave, one thread/row)
constexpr int TILE_FLOATS = RPW * D;   // 4160 floats = 16640 B
constexpr int NBLOCKS = 1792;          // 7 single-wave blocks/CU x 256 CU (LDS-capped)

// ---------------------------------------------------------------------------
// Prep: project anchors, write to ws:
//   ws[0 .. A*D)      : transposed  aT[j*A + a]  (wave-uniform s_loads)
//   ws[A*D .. 2*A*D)  : row-major   aRM[a*D + j] (staged to LDS for na)
// ---------------------------------------------------------------------------
__global__ void prep_anchors(const float* __restrict__ anchors,
                             float* __restrict__ ws) {
    __shared__ float s_a[A * D];
    int tid = threadIdx.x;
    for (int i = tid; i < A * D; i += blockDim.x) s_a[i] = anchors[i];
    __syncthreads();
    if (tid < A) {
        float s = 0.f;
        for (int j = 1; j < D; ++j) {
            float v = s_a[tid * D + j];
            s = fmaf(v, v, s);
        }
        s_a[tid * D] = sqrtf(1.f + s);
    }
    __syncthreads();
    for (int i = tid; i < A * D; i += blockDim.x) {
        int a = i / D, j = i % D;
        ws[j * A + a] = s_a[i];    // transposed
        ws[A * D + i] = s_a[i];    // row-major (projected)
    }
}

// ---------------------------------------------------------------------------
// Per-row math (identical to the verified-passing version): 16 Lorentz inner
// products (aT via wave-uniform s_loads), argmin, exp-map update.
// out_j = (ch + sc*xy)*x_j + sc*na_j.
// ---------------------------------------------------------------------------
__device__ __forceinline__ void row_math(const float xr[D],
                                         const float* __restrict__ aT,
                                         const float* __restrict__ anch,
                                         float* __restrict__ orow) {
    float acc[A];
#pragma unroll
    for (int a = 0; a < A; ++a) acc[a] = -xr[0] * aT[a];
#pragma unroll
    for (int j = 1; j < D; ++j) {
        const float xj = xr[j];
#pragma unroll
        for (int a = 0; a < A; ++a)
            acc[a] = fmaf(xj, aT[j * A + a], acc[a]);
    }

    // argmin of acosh(max(-inner,1+eps)); strict < = first-index ties
    const float onePlusEps = 1.0f + EPS;
    float bestZ = fmaxf(-acc[0], onePlusEps);
    float xy = acc[0];
    int bidx = 0;
#pragma unroll
    for (int a = 1; a < A; ++a) {
        float z = fmaxf(-acc[a], onePlusEps);
        if (z < bestZ) { bestZ = z; bidx = a; xy = acc[a]; }
    }
    const float d = acoshf(bestZ);

    // na reads: same-bidx lanes broadcast; distinct bidx (<16) at fixed j hit
    // distinct banks ((bidx+j)%32) -> conflict-free
    const float* na = anch + bidx * D;
    float uu;
    {
        float u0 = fmaf(xy, xr[0], na[0]);
        uu = -u0 * u0;
    }
#pragma unroll
    for (int j = 1; j < D; ++j) {
        float uj = fmaf(xy, xr[j], na[j]);
        uu = fmaf(uj, uj, uu);
    }
    const float unorm = sqrtf(fmaxf(uu, EPS));
    const float c = ALPHA * d / unorm;
    const float vv = c * c * uu;
    const float vn = sqrtf(fmaxf(vv, EPS * EPS));
    const float sinhc = (vn > EPS) ? (sinhf(vn) / vn) : 1.0f;
    const float ch = coshf(vn);
    const float sc = sinhc * c;
    const float k1 = fmaf(sc, xy, ch);    // ch + sc*xy
#pragma unroll
    for (int j = 0; j < D; ++j)
        orow[j] = fmaf(k1, xr[j], sc * na[j]);
}

// ---------------------------------------------------------------------------
// Main: persistent single-wave blocks, grid-stride over 64-row tiles.
// REG-STAGED prefetch (no global_load_lds): per iteration,
//   1. issue 17 coalesced global_load_dwordx4 for tile t+stride into VGPRs
//      (global->VGPR touches no LDS, so the compiler inserts NO vmem wait
//      before the compute-phase ds_reads — the round-2 serialization bug),
//   2. compute tile t entirely from/into the single LDS buffer,
//   3. ds_write the prefetched regs into LDS for the next iteration; the
//      compiler's only required vmem wait lands here, and because the 17
//      loads are OLDER than the 17 stores issued in step 2, that wait is
//      vmcnt(17): stores stay in flight, load latency hid under compute.
// Single LDS buffer (VGPRs are the second buffer): 16640 + 4160 B
// -> 7 blocks/CU -> ~100 KB of loads in flight per CU >> Little's-law ~9 KB.
// ---------------------------------------------------------------------------
__global__ __launch_bounds__(64, 1) void
homeo_kernel(const float* __restrict__ x,
             const float* __restrict__ aT,    // [D][A] transposed, projected
             const float* __restrict__ aRM,   // [A][D] row-major, projected
             float* __restrict__ out, int B) {
    __shared__ float buf[TILE_FLOATS];        // 16640 B
    __shared__ float anch[A * D];             // 4160 B -> 20800 B/block

    const int lane = threadIdx.x;             // 0..63, one wave per block
    const long stride = gridDim.x;
    const int nTiles = (B + RPW - 1) / RPW;

    // anchors -> LDS. Single wave per block: DS pipe is in-order per wave and
    // lgkmcnt ordering is compiler-inserted — no barrier needed anywhere.
    for (int i = lane; i < A * D; i += 64) anch[i] = aRM[i];

    float4 sv[16];
    float stail = 0.f;

    // prologue: stage tile t0 through regs into LDS
    {
        const long t0 = blockIdx.x;
        if (t0 < nTiles && (t0 + 1) * (long)RPW <= (long)B) {
            const float* g = x + t0 * (long)TILE_FLOATS;
#pragma unroll
            for (int c = 0; c < 16; ++c)
                sv[c] = *reinterpret_cast<const float4*>(g + (c * 64 + lane) * 4);
            stail = g[16 * 256 + lane];
#pragma unroll
            for (int c = 0; c < 16; ++c)
                *reinterpret_cast<float4*>(buf + (c * 64 + lane) * 4) = sv[c];
            buf[16 * 256 + lane] = stail;
        }
    }

    for (long t = blockIdx.x; t < nTiles; t += stride) {
        const long rowStart = t * RPW;
        const int nRows = (int)min((long)RPW, (long)B - rowStart);

        // ---- step 1: prefetch next tile into registers (issue-early) ----
        const long tn = t + stride;
        const bool pre = (tn < nTiles) && ((tn + 1) * (long)RPW <= (long)B);
        if (pre) {
            const float* g = x + tn * (long)TILE_FLOATS;
#pragma unroll
            for (int c = 0; c < 16; ++c)
                sv[c] = *reinterpret_cast<const float4*>(g + (c * 64 + lane) * 4);
            stail = g[16 * 256 + lane];
        }

        // ---- step 2: compute tile t from LDS ----
        if (nRows == RPW) {
            // row into registers: bank = (lane + j) % 32 -> 2-way, free
            float xr[D];
#pragma unroll
            for (int j = 0; j < D; ++j) xr[j] = buf[lane * D + j];

            // result written back in place (reads fully consumed into xr)
            row_math(xr, aT, anch, buf + lane * D);

            // wave-local fence: all lanes' LDS writes retired before
            // cross-lane reads in the coalesced store below
            asm volatile("s_waitcnt lgkmcnt(0)" ::: "memory");

            float4* o4 = (float4*)(out + rowStart * (long)D);
            const float4* l4 = (const float4*)buf;
#pragma unroll
            for (int c2 = 0; c2 < 16; ++c2)
                o4[c2 * 64 + lane] = l4[c2 * 64 + lane];
            out[rowStart * (long)D + 16 * 256 + lane] = buf[16 * 256 + lane];
        } else if (lane < nRows) {
            // partial tile (unused at B=1e6): global direct, no LDS
            const float* xg = x + (rowStart + lane) * (long)D;
            float xr[D];
            for (int j = 0; j < D; ++j) xr[j] = xg[j];
            row_math(xr, aT, anch, out + (rowStart + lane) * (long)D);
        }

        // ---- step 3: write prefetched tile into LDS (write-late). The
        // compiler's vmcnt wait for sv lands here; DS pipe in-order per wave
        // orders these writes after the out-reads above; global stores
        // captured their data at issue. ----
        if (pre) {
#pragma unroll
            for (int c = 0; c < 16; ++c)
                *reinterpret_cast<float4*>(buf + (c * 64 + lane) * 4) = sv[c];
            buf[16 * 256 + lane] = stail;
        }
    }
}

extern "C" void kernel_launch(void* const* d_in, const int* in_sizes, int n_in,
                              void* d_out, int out_size, void* d_ws, size_t ws_size,
                              hipStream_t stream) {
    const float* hyp = (const float*)d_in[0];
    const float* anchors = (const float*)d_in[1];
    float* out = (float*)d_out;
    float* ws = (float*)d_ws;

    const int B = in_sizes[0] / D;                 // 1,000,000
    const int nTiles = (B + RPW - 1) / RPW;        // 15,625 tiles
    const int grid = nTiles < NBLOCKS ? nTiles : NBLOCKS;

    prep_anchors<<<1, 256, 0, stream>>>(anchors, ws);
    homeo_kernel<<<grid, 64, 0, stream>>>(hyp, ws, ws + A * D, out, B);
}

// Round 4
// 440.498 us; speedup vs baseline: 1.1034x; 1.1034x over previous
//
#include <hip/hip_runtime.h>
#include <math.h>
#include <stdint.h>

#define ALPHA 0.1f
#define EPS 1e-7f

constexpr int D = 65;                  // 1 time-like + 64 space dims
constexpr int A = 16;                  // anchors
constexpr int RPW = 64;                // rows per tile (one wave, one thread/row)
constexpr int TILE_FLOATS = RPW * D;   // 4160 floats = 16640 B

// ---------------------------------------------------------------------------
// async global->LDS DMA helpers (gfx950: size 4 or 16). LDS dest is
// wave-uniform base + lane*size; global addr is per-lane.
// ---------------------------------------------------------------------------
__device__ __forceinline__ void async_cp16(const float* g, float* l) {
    __builtin_amdgcn_global_load_lds(
        (const __attribute__((address_space(1))) uint32_t*)(uintptr_t)g,
        (__attribute__((address_space(3))) uint32_t*)(uint32_t)(uintptr_t)l,
        16, 0, 0);
}
__device__ __forceinline__ void async_cp4(const float* g, float* l) {
    __builtin_amdgcn_global_load_lds(
        (const __attribute__((address_space(1))) uint32_t*)(uintptr_t)g,
        (__attribute__((address_space(3))) uint32_t*)(uint32_t)(uintptr_t)l,
        4, 0, 0);
}

// ---------------------------------------------------------------------------
// Prep: project anchors, write to ws:
//   ws[0 .. A*D)      : transposed  aT[j*A + a]  (wave-uniform s_loads)
//   ws[A*D .. 2*A*D)  : row-major   aRM[a*D + j] (staged to LDS for na)
// ---------------------------------------------------------------------------
__global__ void prep_anchors(const float* __restrict__ anchors,
                             float* __restrict__ ws) {
    __shared__ float s_a[A * D];
    int tid = threadIdx.x;
    for (int i = tid; i < A * D; i += blockDim.x) s_a[i] = anchors[i];
    __syncthreads();
    if (tid < A) {
        float s = 0.f;
        for (int j = 1; j < D; ++j) {
            float v = s_a[tid * D + j];
            s = fmaf(v, v, s);
        }
        s_a[tid * D] = sqrtf(1.f + s);
    }
    __syncthreads();
    for (int i = tid; i < A * D; i += blockDim.x) {
        int a = i / D, j = i % D;
        ws[j * A + a] = s_a[i];    // transposed
        ws[A * D + i] = s_a[i];    // row-major (projected)
    }
}

// ---------------------------------------------------------------------------
// Per-row math (identical to the verified-passing version): 16 Lorentz inner
// products (aT via wave-uniform s_loads), argmin, exp-map update.
// out_j = (ch + sc*xy)*x_j + sc*na_j.
// ---------------------------------------------------------------------------
__device__ __forceinline__ void row_math(const float xr[D],
                                         const float* __restrict__ aT,
                                         const float* __restrict__ anch,
                                         float* __restrict__ orow) {
    float acc[A];
#pragma unroll
    for (int a = 0; a < A; ++a) acc[a] = -xr[0] * aT[a];
#pragma unroll
    for (int j = 1; j < D; ++j) {
        const float xj = xr[j];
#pragma unroll
        for (int a = 0; a < A; ++a)
            acc[a] = fmaf(xj, aT[j * A + a], acc[a]);
    }

    // argmin of acosh(max(-inner,1+eps)); strict < = first-index ties
    const float onePlusEps = 1.0f + EPS;
    float bestZ = fmaxf(-acc[0], onePlusEps);
    float xy = acc[0];
    int bidx = 0;
#pragma unroll
    for (int a = 1; a < A; ++a) {
        float z = fmaxf(-acc[a], onePlusEps);
        if (z < bestZ) { bestZ = z; bidx = a; xy = acc[a]; }
    }
    const float d = acoshf(bestZ);

    // na reads: same-bidx lanes broadcast; distinct bidx (<16) at fixed j hit
    // distinct banks ((bidx+j)%32) -> conflict-free
    const float* na = anch + bidx * D;
    float uu;
    {
        float u0 = fmaf(xy, xr[0], na[0]);
        uu = -u0 * u0;
    }
#pragma unroll
    for (int j = 1; j < D; ++j) {
        float uj = fmaf(xy, xr[j], na[j]);
        uu = fmaf(uj, uj, uu);
    }
    const float unorm = sqrtf(fmaxf(uu, EPS));
    const float c = ALPHA * d / unorm;
    const float vv = c * c * uu;
    const float vn = sqrtf(fmaxf(vv, EPS * EPS));
    const float sinhc = (vn > EPS) ? (sinhf(vn) / vn) : 1.0f;
    const float ch = coshf(vn);
    const float sc = sinhc * c;
    const float k1 = fmaf(sc, xy, ch);    // ch + sc*xy
#pragma unroll
    for (int j = 0; j < D; ++j)
        orow[j] = fmaf(k1, xr[j], sc * na[j]);
}

// ---------------------------------------------------------------------------
// Main: ONE-SHOT single-wave blocks, one 64-row tile per block, ZERO barriers.
// grid = nTiles = 15625. LDS 20.8 KB/block -> 7 independent waves/CU.
//
// Rationale (rounds 2-3 post-mortems): intra-wave software pipelining is
// defeated by the compiler either way — global_load_lds double-buffer gets a
// conservative vmcnt(0) before the compute ds_reads (round 2, serialized),
// and reg-staged prefetch spills its 64-VGPR tile to scratch (round 3,
// WRITE_SIZE 2x). Here the compiler's mandatory vmcnt(0) before the ds_reads
// is exactly the semantics we need (wait own DMA), and latency hiding comes
// from 7 phase-drifted independent waves per CU instead of in-wave overlap.
// Per-CU roofline: 61 tiles x 3250 cy mem vs 22% VALU load -> memory-bound.
// ---------------------------------------------------------------------------
__global__ __launch_bounds__(64, 1) void
homeo_kernel(const float* __restrict__ x,
             const float* __restrict__ aT,    // [D][A] transposed, projected
             const float* __restrict__ aRM,   // [A][D] row-major, projected
             float* __restrict__ out, int B) {
    __shared__ float buf[TILE_FLOATS];        // 16640 B
    __shared__ float anch[A * D];             // 4160 B -> 20800 B/block

    const int lane = threadIdx.x;             // 0..63, one wave per block
    const long t = blockIdx.x;                // this block's tile
    const long rowStart = t * RPW;
    const int nRows = (int)min((long)RPW, (long)B - rowStart);
    const bool full = (nRows == RPW);

    // ---- issue this tile's DMA first: bytes start flowing immediately ----
    if (full) {
        const float* g = x + rowStart * (long)D;
#pragma unroll
        for (int c = 0; c < 16; ++c)
            async_cp16(g + c * 256 + lane * 4, buf + c * 256);
        async_cp4(g + 16 * 256 + lane, buf + 16 * 256);
    }

    // ---- anchors -> LDS (L2-hot, overlaps DMA flight). Single wave: DS
    // ordering within the wave is handled by compiler-inserted lgkmcnt. ----
    for (int i = lane; i < A * D; i += 64) anch[i] = aRM[i];

    if (full) {
        // compiler inserts the (required) vmcnt wait before these ds_reads.
        // bank = (lane*65 + j) % 32 = (lane + j) % 32 -> 2-way, free
        float xr[D];
#pragma unroll
        for (int j = 0; j < D; ++j) xr[j] = buf[lane * D + j];

        // result written back in place (reads fully consumed into xr)
        row_math(xr, aT, anch, buf + lane * D);

        // wave-local fence: all lanes' LDS writes retired before the
        // cross-lane reads in the coalesced store below
        asm volatile("s_waitcnt lgkmcnt(0)" ::: "memory");

        float4* o4 = (float4*)(out + rowStart * (long)D);
        const float4* l4 = (const float4*)buf;
#pragma unroll
        for (int c2 = 0; c2 < 16; ++c2)
            o4[c2 * 64 + lane] = l4[c2 * 64 + lane];
        out[rowStart * (long)D + 16 * 256 + lane] = buf[16 * 256 + lane];
    } else if (lane < nRows) {
        // partial tile (unused at B=1e6: 15625 full tiles exactly):
        // direct global read/write, no LDS staging
        const float* xg = x + (rowStart + lane) * (long)D;
        float xr[D];
        for (int j = 0; j < D; ++j) xr[j] = xg[j];
        row_math(xr, aT, anch, out + (rowStart + lane) * (long)D);
    }
}

extern "C" void kernel_launch(void* const* d_in, const int* in_sizes, int n_in,
                              void* d_out, int out_size, void* d_ws, size_t ws_size,
                              hipStream_t stream) {
    const float* hyp = (const float*)d_in[0];
    const float* anchors = (const float*)d_in[1];
    float* out = (float*)d_out;
    float* ws = (float*)d_ws;

    const int B = in_sizes[0] / D;                 // 1,000,000
    const int nTiles = (B + RPW - 1) / RPW;        // 15,625 tiles = grid

    prep_anchors<<<1, 256, 0, stream>>>(anchors, ws);
    homeo_kernel<<<nTiles, 64, 0, stream>>>(hyp, ws, ws + A * D, out, B);
}